// Round 8
// baseline (180.755 us; speedup 1.0000x reference)
//
#include <hip/hip_runtime.h>
#include <hip/hip_bf16.h>

#define HID 16
#define DIN 64
#define NK  32
#define NB  8192

typedef float v4f __attribute__((ext_vector_type(4)));

// Hinge form of one inner MLP (k, d=lane):
//   sum_h w2*relu(w1*x+b1) = A*x + B + sum_h u_h*|x + c_h|
struct PW {
    float A, B;
    float u[HID];
    float c[HID];
};

__device__ __forceinline__ float pl_eval(const PW& w, float xd) {
    float a0 = fmaf(w.A, xd, w.B);
    float a1 = 0.f;
    #pragma unroll
    for (int h = 0; h < HID; h += 2) {
        const float t0 = xd + w.c[h];
        const float t1 = xd + w.c[h + 1];
        a0 = fmaf(fabsf(t0), w.u[h],     a0);
        a1 = fmaf(fabsf(t1), w.u[h + 1], a1);
    }
    return a0 + a1;
}

// TLP A/B vs round 7: same algorithm, 32 rows/wave (2 passes of 16),
// 2048 blocks, 8 waves/SIMD (VGPR budget <= 64, no SW prefetch array —
// TLP is the latency-hiding mechanism now).
__global__ __launch_bounds__(256, 8) void kan_kernel(
    const float* __restrict__ x,
    const float* __restrict__ iw1, const float* __restrict__ ib1,
    const float* __restrict__ iw2, const float* __restrict__ ib2,
    const float* __restrict__ ow1, const float* __restrict__ ob1,
    const float* __restrict__ ow2, const float* __restrict__ ob2,
    float* __restrict__ out)
{
    __shared__ float lds[4][DIN * 17];

    const int t    = threadIdx.x;
    const int lane = t & 63;
    const int wid  = t >> 6;
    const int k    = blockIdx.x & (NK - 1);
    const int base = ((blockIdx.x >> 5) * 4 + wid) * 32;   // wave's 32 rows

    // ---- per-lane hinge precompute (amortized over 32 rows) ----
    PW w;
    {
        v4f w1v[4], b1v[4], w2v[4];
        const v4f* p1 = (const v4f*)(iw1 + (k * DIN + lane) * HID);
        const v4f* p2 = (const v4f*)(ib1 + (k * DIN + lane) * HID);
        const v4f* p3 = (const v4f*)(iw2 + (k * DIN + lane) * HID);
        #pragma unroll
        for (int q = 0; q < 4; ++q) { w1v[q] = p1[q]; b1v[q] = p2[q]; w2v[q] = p3[q]; }

        float A = 0.f;
        float B = ib2[k * DIN + lane];   // fold inner L2 bias
        #pragma unroll
        for (int h = 0; h < HID; ++h) {
            const float w1  = w1v[h >> 2][h & 3];
            const float b1  = b1v[h >> 2][h & 3];
            const float w2h = w2v[h >> 2][h & 3];
            A = fmaf(0.5f * w2h, w1, A);
            B = fmaf(0.5f * w2h, b1, B);
            const float aw = fabsf(w1);
            const bool ok  = aw > 1e-20f;
            w.c[h] = ok ? b1 * __builtin_amdgcn_rcpf(w1) : 0.f;
            w.u[h] = ok ? 0.5f * w2h * aw : 0.f;
            if (!ok) B = fmaf(0.5f * w2h, fabsf(b1), B);
        }
        w.A = A; w.B = B;
    }

    float* __restrict__ myLds = lds[wid];
    const float* __restrict__ xp = x + base * DIN + lane;

    const int jj  = lane & 15;                 // row slot this lane reduces
    const int pgr = lane >> 4;                 // d-group this lane sums
    float* __restrict__ wb = myLds + lane * 17;
    const float* __restrict__ rb = myLds + (pgr * 16) * 17 + jj;
    const int mypass = (lane >> 4) & 1;        // pass that owns row lane&31

    float sk = 0.f;

    #pragma clang loop unroll(disable)
    for (int p = 0; p < 2; ++p) {
        const float* __restrict__ xq = xp + p * 16 * DIN;
        float xr[16];
        #pragma unroll
        for (int j = 0; j < 16; ++j) xr[j] = xq[j * DIN];
        #pragma unroll
        for (int j = 0; j < 16; ++j) wb[j] = pl_eval(w, xr[j]);
        float s = 0.f;
        #pragma unroll
        for (int i = 0; i < 16; ++i) s += rb[i * 17];
        s += __shfl_xor(s, 16, 64);
        s += __shfl_xor(s, 32, 64);
        sk = (p == mypass) ? s : sk;           // lane keeps its own row's pass
    }

    // Outer net: scalar -> HID -> scalar (per k)
    float o = ob2[k];
    #pragma unroll
    for (int h = 0; h < HID; ++h) {
        const float g = fmaxf(fmaf(sk, ow1[k * HID + h], ob1[k * HID + h]), 0.f);
        o = fmaf(g, ow2[k * HID + h], o);
    }

    if (lane < 32) {
        out[(base + lane) * NK + k] = o;
    }
}

extern "C" void kernel_launch(void* const* d_in, const int* in_sizes, int n_in,
                              void* d_out, int out_size, void* d_ws, size_t ws_size,
                              hipStream_t stream) {
    const float* x   = (const float*)d_in[0];
    const float* iw1 = (const float*)d_in[1];
    const float* ib1 = (const float*)d_in[2];
    const float* iw2 = (const float*)d_in[3];
    const float* ib2 = (const float*)d_in[4];
    const float* ow1 = (const float*)d_in[5];
    const float* ob1 = (const float*)d_in[6];
    const float* ow2 = (const float*)d_in[7];
    const float* ob2 = (const float*)d_in[8];
    float* out = (float*)d_out;

    const int grid = (NB / 128) * NK;  // 64 chunks * 32 k = 2048 blocks
    kan_kernel<<<grid, 256, 0, stream>>>(x, iw1, ib1, iw2, ib2,
                                         ow1, ob1, ow2, ob2, out);
}

// Round 9
// 26.835 us; speedup vs baseline: 6.7357x; 6.7357x over previous
//
#include <hip/hip_runtime.h>
#include <hip/hip_bf16.h>

#define HID 16
#define DIN 64
#define NK  32
#define NB  8192

typedef float v4f __attribute__((ext_vector_type(4)));

// Hinge form of one inner MLP (k, d=lane):
//   sum_h w2*relu(w1*x+b1) = A*x + B + sum_h u_h*|x + c_h|
struct PW {
    float A, B;
    float u[HID];
    float c[HID];
};

__device__ __forceinline__ float pl_eval(const PW& w, float xd) {
    float a0 = fmaf(w.A, xd, w.B);
    float a1 = 0.f;
    #pragma unroll
    for (int h = 0; h < HID; h += 2) {
        const float t0 = xd + w.c[h];
        const float t1 = xd + w.c[h + 1];
        a0 = fmaf(fabsf(t0), w.u[h],     a0);
        a1 = fmaf(fabsf(t1), w.u[h + 1], a1);
    }
    return a0 + a1;
}

// lane = d, hinge weights in VGPRs. Double-buffered LDS transpose, statically
// software-pipelined so each pass's reduce tail (lgkm wait + reads + shuffles)
// hides under the next pass's pure-VALU eval. DS pipe is in-order per wave,
// so read-before-overwrite needs no barrier.
__global__ __launch_bounds__(256, 4) void kan_kernel(
    const float* __restrict__ x,
    const float* __restrict__ iw1, const float* __restrict__ ib1,
    const float* __restrict__ iw2, const float* __restrict__ ib2,
    const float* __restrict__ ow1, const float* __restrict__ ob1,
    const float* __restrict__ ow2, const float* __restrict__ ob2,
    float* __restrict__ out)
{
    __shared__ float lds[4][2][DIN * 17];

    const int t    = threadIdx.x;
    const int lane = t & 63;
    const int wid  = t >> 6;
    const int k    = blockIdx.x & (NK - 1);
    const int base = ((blockIdx.x >> 5) * 4 + wid) * 64;   // wave's 64 rows

    // ---- per-lane hinge precompute (once per wave) ----
    PW w;
    {
        v4f w1v[4], b1v[4], w2v[4];
        const v4f* p1 = (const v4f*)(iw1 + (k * DIN + lane) * HID);
        const v4f* p2 = (const v4f*)(ib1 + (k * DIN + lane) * HID);
        const v4f* p3 = (const v4f*)(iw2 + (k * DIN + lane) * HID);
        #pragma unroll
        for (int q = 0; q < 4; ++q) { w1v[q] = p1[q]; b1v[q] = p2[q]; w2v[q] = p3[q]; }

        float A = 0.f;
        float B = ib2[k * DIN + lane];   // fold inner L2 bias
        #pragma unroll
        for (int h = 0; h < HID; ++h) {
            const float w1  = w1v[h >> 2][h & 3];
            const float b1  = b1v[h >> 2][h & 3];
            const float w2h = w2v[h >> 2][h & 3];
            A = fmaf(0.5f * w2h, w1, A);
            B = fmaf(0.5f * w2h, b1, B);
            const float aw = fabsf(w1);
            const bool ok  = aw > 1e-20f;
            w.c[h] = ok ? b1 * __builtin_amdgcn_rcpf(w1) : 0.f;
            w.u[h] = ok ? 0.5f * w2h * aw : 0.f;
            if (!ok) B = fmaf(0.5f * w2h, fabsf(b1), B);
        }
        w.A = A; w.B = B;
    }

    const float* __restrict__ xp = x + base * DIN + lane;

    const int jj  = lane & 15;           // row slot this lane reduces
    const int pgr = lane >> 4;           // d-group this lane sums

    float* __restrict__ wb0 = &lds[wid][0][lane * 17];
    float* __restrict__ wb1 = &lds[wid][1][lane * 17];
    const float* __restrict__ rb0 = &lds[wid][0][(pgr * 16) * 17 + jj];
    const float* __restrict__ rb1 = &lds[wid][1][(pgr * 16) * 17 + jj];

    float xa[16], xb[16];
    float rsum[4];

    // ---- static pipeline over 4 passes of 16 rows ----
    #pragma unroll
    for (int j = 0; j < 16; ++j) xa[j] = xp[(0 * 16 + j) * DIN];
    #pragma unroll
    for (int j = 0; j < 16; ++j) xb[j] = xp[(1 * 16 + j) * DIN];

    // eval p0 -> buf0
    #pragma unroll
    for (int j = 0; j < 16; ++j) wb0[j] = pl_eval(w, xa[j]);
    // prefetch p2 (xa regs dead after eval p0)
    #pragma unroll
    for (int j = 0; j < 16; ++j) xa[j] = xp[(2 * 16 + j) * DIN];
    // eval p1 -> buf1
    #pragma unroll
    for (int j = 0; j < 16; ++j) wb1[j] = pl_eval(w, xb[j]);
    // prefetch p3
    #pragma unroll
    for (int j = 0; j < 16; ++j) xb[j] = xp[(3 * 16 + j) * DIN];

    // reduce macro body: tree-sum 16 strided reads + 2 shuffles
    auto reduce = [&](const float* rb) -> float {
        float v[16];
        #pragma unroll
        for (int i = 0; i < 16; ++i) v[i] = rb[i * 17];
        #pragma unroll
        for (int m = 8; m; m >>= 1)
            #pragma unroll
            for (int i = 0; i < m; ++i) v[i] += v[i + m];
        float s = v[0];
        s += __shfl_xor(s, 16, 64);
        s += __shfl_xor(s, 32, 64);
        return s;
    };

    rsum[0] = reduce(rb0);               // reduce p0 (overlaps eval p2 below)
    #pragma unroll
    for (int j = 0; j < 16; ++j) wb0[j] = pl_eval(w, xa[j]);   // eval p2 -> buf0
    rsum[1] = reduce(rb1);               // reduce p1 (overlaps eval p3)
    #pragma unroll
    for (int j = 0; j < 16; ++j) wb1[j] = pl_eval(w, xb[j]);   // eval p3 -> buf1
    rsum[2] = reduce(rb0);               // reduce p2
    rsum[3] = reduce(rb1);               // reduce p3

    // Lane l owns row base+l: pass index = l>>4 (static select).
    const float sk = (lane & 32) ? ((lane & 16) ? rsum[3] : rsum[2])
                                 : ((lane & 16) ? rsum[1] : rsum[0]);

    // Outer net: scalar -> HID -> scalar (per k)
    float o = ob2[k];
    #pragma unroll
    for (int h = 0; h < HID; ++h) {
        const float g = fmaxf(fmaf(sk, ow1[k * HID + h], ob1[k * HID + h]), 0.f);
        o = fmaf(g, ow2[k * HID + h], o);
    }

    out[(base + lane) * NK + k] = o;
}

extern "C" void kernel_launch(void* const* d_in, const int* in_sizes, int n_in,
                              void* d_out, int out_size, void* d_ws, size_t ws_size,
                              hipStream_t stream) {
    const float* x   = (const float*)d_in[0];
    const float* iw1 = (const float*)d_in[1];
    const float* ib1 = (const float*)d_in[2];
    const float* iw2 = (const float*)d_in[3];
    const float* ib2 = (const float*)d_in[4];
    const float* ow1 = (const float*)d_in[5];
    const float* ob1 = (const float*)d_in[6];
    const float* ow2 = (const float*)d_in[7];
    const float* ob2 = (const float*)d_in[8];
    float* out = (float*)d_out;

    const int grid = (NB / 256) * NK;  // 1024 blocks, 4 waves each
    kan_kernel<<<grid, 256, 0, stream>>>(x, iw1, ib1, iw2, ib2,
                                         ow1, ob1, ow2, ob2, out);
}